// Round 8
// baseline (51.649 us; speedup 1.0000x reference)
//
#include <hip/hip_runtime.h>

// Daubechies-4 (db2) synthesis filter taps, f32
#define H_0 0.48296291314469025f
#define H_1 0.8365163037378079f
#define H_2 0.22414386804201336f
#define H_3 (-0.12940952255092145f)
#define G_0 (-0.12940952255092145f)
#define G_1 (-0.22414386804201336f)
#define G_2 0.8365163037378079f
#define G_3 (-0.48296291314469025f)

typedef float evf4 __attribute__((ext_vector_type(4)));

// Rolling-stream fused inverse db2 level, register-only, no cross-lane ops.
// One wave owns a 256 t-col segment (lane l -> 4 low cols [cl,cl+4), 4 high
// cols [S2+cl,..)) and walks K consecutive row-pass strips m (compile-time,
// fully unrolled). Row m-1 inputs are register-carried. The col-pass left
// neighbor t[cl-1] is recomputed per lane from 4 scalar loads at input col
// cl-1 (same cache lines as the neighbor lane's vector loads -> L1 hits).
// NTSTORE: final-output stores are nontemporal (out is never re-read) so the
// write stream does not evict the cross-strip read reuse in L2/L3.

__device__ __forceinline__ float4 rowpass4(float h0, float h2, float g0, float g2,
                                           const float4& P, const float4& Q,
                                           const float4& R, const float4& T) {
    return make_float4(h0 * P.x + h2 * Q.x + g0 * R.x + g2 * T.x,
                       h0 * P.y + h2 * Q.y + g0 * R.y + g2 * T.y,
                       h0 * P.z + h2 * Q.z + g0 * R.z + g2 * T.z,
                       h0 * P.w + h2 * Q.w + g0 * R.w + g2 * T.w);
}

template <bool NT>
__device__ __forceinline__ void colpass_store(float* __restrict__ dst,
                                              const float4 L, const float Lm1,
                                              const float4 Hi, const float Hm1) {
    float4 s0, s1;
    s0.x = H_0 * L.x + H_2 * Lm1 + G_0 * Hi.x + G_2 * Hm1;
    s0.y = H_1 * L.x + H_3 * Lm1 + G_1 * Hi.x + G_3 * Hm1;
    s0.z = H_0 * L.y + H_2 * L.x + G_0 * Hi.y + G_2 * Hi.x;
    s0.w = H_1 * L.y + H_3 * L.x + G_1 * Hi.y + G_3 * Hi.x;
    s1.x = H_0 * L.z + H_2 * L.y + G_0 * Hi.z + G_2 * Hi.y;
    s1.y = H_1 * L.z + H_3 * L.y + G_1 * Hi.z + G_3 * Hi.y;
    s1.z = H_0 * L.w + H_2 * L.z + G_0 * Hi.w + G_2 * Hi.z;
    s1.w = H_1 * L.w + H_3 * L.z + G_1 * Hi.w + G_3 * Hi.z;
    if constexpr (NT) {
        __builtin_nontemporal_store(*reinterpret_cast<evf4*>(&s0),
                                    reinterpret_cast<evf4*>(dst));
        __builtin_nontemporal_store(*reinterpret_cast<evf4*>(&s1),
                                    reinterpret_cast<evf4*>(dst + 4));
    } else {
        *reinterpret_cast<float4*>(dst) = s0;
        *reinterpret_cast<float4*>(dst + 4) = s1;
    }
}

template <int K, bool NT>
__global__ __launch_bounds__(256) void iwt_roll(
    const float* __restrict__ x, int ldx,
    const float* __restrict__ sub, int ldsub,
    float* __restrict__ out, int ldo,
    int S2, int segShift) {
    const int lane = threadIdx.x & 63;
    const int wid = (blockIdx.x * 256 + threadIdx.x) >> 6;   // global wave id
    const int seg = wid & ((1 << segShift) - 1);             // 256-t-col segment
    const int m0 = (wid >> segShift) * K;                    // first strip
    const int cl = (seg << 8) + (lane << 2);                 // lane's low t-col
    const int cm1 = (cl == 0) ? (S2 - 1) : (cl - 1);         // t-col cl-1 (wrapped)

    const bool hasSub = (sub != nullptr);
    const float* __restrict__ pA = hasSub ? sub : x;         // rows<S2, cols<S2
    const int ldA = hasSub ? ldsub : ldx;

    // Prologue: row m0-1 inputs (circular wrap only possible here).
    const int mp0 = (m0 == 0) ? (S2 - 1) : (m0 - 1);
    float4 Ap = *reinterpret_cast<const float4*>(pA + (size_t)mp0 * ldA + cl);
    float4 Bp = *reinterpret_cast<const float4*>(x + (size_t)(S2 + mp0) * ldx + cl);
    float4 Cp = *reinterpret_cast<const float4*>(x + (size_t)mp0 * ldx + S2 + cl);
    float4 Dp = *reinterpret_cast<const float4*>(x + (size_t)(S2 + mp0) * ldx + S2 + cl);
    float ap = pA[(size_t)mp0 * ldA + cm1];
    float bp = x[(size_t)(S2 + mp0) * ldx + cm1];
    float cp = x[(size_t)mp0 * ldx + S2 + cm1];
    float dp = x[(size_t)(S2 + mp0) * ldx + S2 + cm1];

#pragma unroll
    for (int i = 0; i < K; ++i) {
        const int m = m0 + i;
        // 4 coalesced float4 loads + 4 per-lane scalar loads (col cl-1).
        const float4 A = *reinterpret_cast<const float4*>(pA + (size_t)m * ldA + cl);
        const float4 B = *reinterpret_cast<const float4*>(x + (size_t)(S2 + m) * ldx + cl);
        const float4 C = *reinterpret_cast<const float4*>(x + (size_t)m * ldx + S2 + cl);
        const float4 D = *reinterpret_cast<const float4*>(x + (size_t)(S2 + m) * ldx + S2 + cl);
        const float a = pA[(size_t)m * ldA + cm1];
        const float b = x[(size_t)(S2 + m) * ldx + cm1];
        const float c = x[(size_t)m * ldx + S2 + cm1];
        const float d = x[(size_t)(S2 + m) * ldx + S2 + cm1];

        // Row pass -> t rows {2m, 2m+1}, low and high col groups.
        const float4 TL0 = rowpass4(H_0, H_2, G_0, G_2, A, Ap, B, Bp);
        const float4 TL1 = rowpass4(H_1, H_3, G_1, G_3, A, Ap, B, Bp);
        const float4 TH0 = rowpass4(H_0, H_2, G_0, G_2, C, Cp, D, Dp);
        const float4 TH1 = rowpass4(H_1, H_3, G_1, G_3, C, Cp, D, Dp);

        // t at col cl-1 (this lane's col-pass left neighbor), rows {2m, 2m+1}.
        const float mL0 = H_0 * a + H_2 * ap + G_0 * b + G_2 * bp;
        const float mL1 = H_1 * a + H_3 * ap + G_1 * b + G_3 * bp;
        const float mH0 = H_0 * c + H_2 * cp + G_0 * d + G_2 * dp;
        const float mH1 = H_1 * c + H_3 * cp + G_1 * d + G_3 * dp;

        // Col pass + store: rows 2m, 2m+1, cols [2*cl, 2*cl+8).
        float* o0 = out + (size_t)(2 * m) * ldo + 2 * cl;
        colpass_store<NT>(o0, TL0, mL0, TH0, mH0);
        colpass_store<NT>(o0 + ldo, TL1, mL1, TH1, mH1);

        // Roll: current rows become previous rows.
        Ap = A; Bp = B; Cp = C; Dp = D;
        ap = a; bp = b; cp = c; dp = d;
    }
}

extern "C" void kernel_launch(void* const* d_in, const int* in_sizes, int n_in,
                              void* d_out, int out_size, void* d_ws, size_t ws_size,
                              hipStream_t stream) {
    const float* x = (const float*)d_in[0];   // (1, 4096, 4096) f32
    // d_in[1] = mask, d_in[2] = b : unused; d_in[3] = wavSplit -> levels = 3
    float* out = (float*)d_out;               // 4096 x 4096 f32
    float* buf1 = (float*)d_ws;                                 // 1024^2 f32 (4 MB)
    float* buf2 = (float*)((char*)d_ws + ((size_t)16 << 20));   // 2048^2 f32 (16 MB)

    const int N = 4096;

    // Level 1 (S2=512, 2 segs, K=1): 1024 waves -> 256 blocks. Cached stores
    // (buf1 is re-read by level 2).
    iwt_roll<1, false><<<256, 256, 0, stream>>>(x, N, nullptr, 0, buf1, 1024, 512, 1);
    // Level 2 (S2=1024, 4 segs, K=1): 4096 waves -> 1024 blocks. Cached stores.
    iwt_roll<1, false><<<1024, 256, 0, stream>>>(x, N, buf1, 1024, buf2, 2048, 1024, 2);
    // Level 3 (S2=2048, 8 segs, K=2): 8192 waves -> 2048 blocks (8 blocks/CU,
    // 32 waves/CU). Nontemporal stores: out is never re-read.
    iwt_roll<2, true><<<2048, 256, 0, stream>>>(x, N, buf2, 2048, out, N, 2048, 3);
}

// Round 9
// 45.217 us; speedup vs baseline: 1.1422x; 1.1422x over previous
//
#include <hip/hip_runtime.h>

// Daubechies-4 (db2) synthesis filter taps, f32
#define H_0 0.48296291314469025f
#define H_1 0.8365163037378079f
#define H_2 0.22414386804201336f
#define H_3 (-0.12940952255092145f)
#define G_0 (-0.12940952255092145f)
#define G_1 (-0.22414386804201336f)
#define G_2 0.8365163037378079f
#define G_3 (-0.48296291314469025f)

// Full-width strip-fused inverse db2 level.
// One block owns P row-pass strips (output rows 2*m0 .. 2*m0+2P-1) across the
// ENTIRE width S. Row pass -> LDS t[P][2][S]; one barrier; col pass -> out.
// No column halos: the circular col wrap is an LDS index wrap. No cross-lane
// ops, no divergent halo tasks. Every level does exactly 2 row-tasks + 2
// col-tasks per thread (P*S = 8192/LDS budget keeps this uniform).
//
// __launch_bounds__(T, 8): cap VGPR at 64 -> 32 waves/CU; with 64 KB LDS two
// blocks co-reside per CU, so one block's global loads overlap the other
// block's col-pass + stores (no global-memory dead time at barriers).

__device__ __forceinline__ float4 rowpass4(float h0, float h2, float g0, float g2,
                                           const float4& P_, const float4& Q_,
                                           const float4& R_, const float4& T_) {
    return make_float4(h0 * P_.x + h2 * Q_.x + g0 * R_.x + g2 * T_.x,
                       h0 * P_.y + h2 * Q_.y + g0 * R_.y + g2 * T_.y,
                       h0 * P_.z + h2 * Q_.z + g0 * R_.z + g2 * T_.z,
                       h0 * P_.w + h2 * Q_.w + g0 * R_.w + g2 * T_.w);
}

template <int S2, int P, int T>
__global__ __launch_bounds__(T, 8) void iwt_strip(
    const float* __restrict__ x, int ldx,
    const float* __restrict__ sub, int ldsub,
    float* __restrict__ out, int ldo) {
    constexpr int S = 2 * S2;
    constexpr int Q = S2 / 4;          // quad-col groups per half
    constexpr int RT = P * S2 / 2;     // row tasks == col tasks
    constexpr int ITER = RT / T;       // == 2 for all instantiations

    __shared__ float tl[P][2][S];

    const int tid = threadIdx.x;
    const int m0 = blockIdx.x * P;
    const bool hasSub = (sub != nullptr);
    const float* __restrict__ pA = hasSub ? sub : x;   // rows<S2, cols<S2 source
    const int ldA = hasSub ? ldsub : ldx;

    // ---- Row pass -> LDS. Task rt: strip p, half (low/high cols), quad q.
#pragma unroll
    for (int k = 0; k < ITER; ++k) {
        const int rt = tid + k * T;
        const int q = rt % Q;
        const int half = (rt / Q) % 2;
        const int p = rt / (2 * Q);
        const int m = m0 + p;
        const int mp = (m == 0) ? (S2 - 1) : (m - 1);   // circular (block 0 only)
        const int cb = 4 * q;
        const int xcb = half ? (S2 + cb) : cb;          // input col / LDS col

        float4 A, Apv;
        if (half == 0) {   // low cols: from sub (prev level) when present
            A   = *reinterpret_cast<const float4*>(pA + (size_t)m  * ldA + cb);
            Apv = *reinterpret_cast<const float4*>(pA + (size_t)mp * ldA + cb);
        } else {           // high cols: always from x
            A   = *reinterpret_cast<const float4*>(x + (size_t)m  * ldx + xcb);
            Apv = *reinterpret_cast<const float4*>(x + (size_t)mp * ldx + xcb);
        }
        // High-row inputs (row >= S2): always from x.
        const float4 B  = *reinterpret_cast<const float4*>(x + (size_t)(S2 + m)  * ldx + xcb);
        const float4 Bp = *reinterpret_cast<const float4*>(x + (size_t)(S2 + mp) * ldx + xcb);

        const float4 t0 = rowpass4(H_0, H_2, G_0, G_2, A, Apv, B, Bp);
        const float4 t1 = rowpass4(H_1, H_3, G_1, G_3, A, Apv, B, Bp);
        *reinterpret_cast<float4*>(&tl[p][0][xcb]) = t0;
        *reinterpret_cast<float4*>(&tl[p][1][xcb]) = t1;
    }
    __syncthreads();

    // ---- Col pass from LDS -> out. Task ct: t-row (p, orr), col group cg
    // (8 outputs at cols 8cg..8cg+7 from t cols {4cg-1..4cg+3} low & high).
#pragma unroll
    for (int k = 0; k < ITER; ++k) {
        const int ct = tid + k * T;
        const int cg = ct % Q;
        const int r2 = ct / Q;            // in [0, 2P)
        const int p = r2 >> 1;
        const int orr = r2 & 1;
        const int n0 = 4 * cg;
        const int np = (n0 == 0) ? (S2 - 4) : (n0 - 4);   // circular col wrap

        const float* trow = tl[p][orr];
        const float4 L  = *reinterpret_cast<const float4*>(&trow[n0]);
        const float4 Lp = *reinterpret_cast<const float4*>(&trow[np]);
        const float4 Hi = *reinterpret_cast<const float4*>(&trow[S2 + n0]);
        const float4 Hp = *reinterpret_cast<const float4*>(&trow[S2 + np]);
        const float Lm1 = Lp.w, Hm1 = Hp.w;

        float4 s0, s1;
        s0.x = H_0 * L.x + H_2 * Lm1 + G_0 * Hi.x + G_2 * Hm1;
        s0.y = H_1 * L.x + H_3 * Lm1 + G_1 * Hi.x + G_3 * Hm1;
        s0.z = H_0 * L.y + H_2 * L.x + G_0 * Hi.y + G_2 * Hi.x;
        s0.w = H_1 * L.y + H_3 * L.x + G_1 * Hi.y + G_3 * Hi.x;
        s1.x = H_0 * L.z + H_2 * L.y + G_0 * Hi.z + G_2 * Hi.y;
        s1.y = H_1 * L.z + H_3 * L.y + G_1 * Hi.z + G_3 * Hi.y;
        s1.z = H_0 * L.w + H_2 * L.z + G_0 * Hi.w + G_2 * Hi.z;
        s1.w = H_1 * L.w + H_3 * L.z + G_1 * Hi.w + G_3 * Hi.z;

        float* o = out + (size_t)(2 * (m0 + p) + orr) * ldo + 8 * cg;
        *reinterpret_cast<float4*>(o) = s0;
        *reinterpret_cast<float4*>(o + 4) = s1;
    }
}

extern "C" void kernel_launch(void* const* d_in, const int* in_sizes, int n_in,
                              void* d_out, int out_size, void* d_ws, size_t ws_size,
                              hipStream_t stream) {
    const float* x = (const float*)d_in[0];   // (1, 4096, 4096) f32
    // d_in[1] = mask, d_in[2] = b : unused; d_in[3] = wavSplit -> levels = 3
    float* out = (float*)d_out;               // 4096 x 4096 f32
    float* buf1 = (float*)d_ws;                                 // 1024^2 f32 (4 MB)
    float* buf2 = (float*)((char*)d_ws + ((size_t)16 << 20));   // 2048^2 f32 (16 MB)

    const int N = 4096;

    // Level 1 (S=1024): 128 blocks x 512 thr, LDS 32 KB. x top-left -> buf1.
    iwt_strip<512, 4, 512><<<128, 512, 0, stream>>>(x, N, nullptr, 0, buf1, 1024);
    // Level 2 (S=2048): 256 blocks x 1024 thr, LDS 64 KB. sub=buf1 -> buf2.
    iwt_strip<1024, 4, 1024><<<256, 1024, 0, stream>>>(x, N, buf1, 1024, buf2, 2048);
    // Level 3 (S=4096): 1024 blocks x 1024 thr, LDS 64 KB. sub=buf2 -> out.
    iwt_strip<2048, 2, 1024><<<1024, 1024, 0, stream>>>(x, N, buf2, 2048, out, N);
}